// Round 16
// baseline (153.343 us; speedup 1.0000x reference)
//
#include <hip/hip_runtime.h>

#define DELTA 1e-6f

// sizes: b=64, m=1024, w=64, r=4, d=512, iface=471
#define NB 64
#define NM 1024
#define NW 64
#define NR 4
#define ND 512
#define NIF 471

typedef unsigned long long ull;

__device__ __forceinline__ float sigmoidf_(float x){ return 1.0f/(1.0f+expf(-x)); }
__device__ __forceinline__ float softplusf_(float x){ return fmaxf(x,0.0f) + log1pf(expf(-fabsf(x))); }

__device__ __forceinline__ float waveSum(float v){
  #pragma unroll
  for(int o=32;o>0;o>>=1) v += __shfl_down(v,o,64);
  return v;
}
__device__ __forceinline__ float waveMax(float v){
  #pragma unroll
  for(int o=32;o>0;o>>=1) v = fmaxf(v, __shfl_down(v,o,64));
  return v;
}
__device__ __forceinline__ ull shflxor64(ull k, int m){
  unsigned lo = (unsigned)(k & 0xffffffffu), hi = (unsigned)(k>>32);
  lo = (unsigned)__shfl_xor((int)lo, m, 64);
  hi = (unsigned)__shfl_xor((int)hi, m, 64);
  return ((ull)hi<<32)|lo;
}

// ---------------- K1: fused iface + wcos, one launch ----------------
// grid (6, NB): role 0/1 = iface halves (+ out zeroing); roles 2..5 = wcos for jt=role-2,
// with the 68 iface columns wcos needs (wkey[64], fg[4]) recomputed INLINE from xi@W —
// removes the iface->wcos launch dependency so both run in one dispatch.
__global__ __launch_bounds__(256) void k_ifw(
    const float* __restrict__ xi, const float* __restrict__ Wm, const float* __restrict__ bW,
    const float* __restrict__ mem, const float* __restrict__ rw_old,
    const float* __restrict__ ww_old, const float* __restrict__ uv,
    float* __restrict__ iface, float4* __restrict__ out4,
    float* __restrict__ uu, float* __restrict__ wcd, float* __restrict__ wcn){
  int role = blockIdx.x, b = blockIdx.y;
  int tid = threadIdx.x;
  __shared__ float xs[ND];
  __shared__ float wkey[NW];
  __shared__ float fgs[4];
  for(int k=tid;k<ND;k+=256) xs[k]=xi[b*ND+k];
  if (role == 0 && tid < 64) out4[b*64 + tid] = make_float4(0.f,0.f,0.f,0.f);
  __syncthreads();
  if (role < 2){
    int c = role*236 + tid;
    int cend = role ? NIF : 236;
    if (c < cend){
      float acc = bW[c];
      #pragma unroll 4
      for(int k=0;k<ND;k++) acc = fmaf(xs[k], Wm[k*NIF+c], acc);
      iface[b*NIF+c]=acc;
    }
    return;
  }
  // wcos path: inline wkey/fg from xi@W
  if (tid < 64){
    int c = 260 + tid;
    float acc = bW[c];
    #pragma unroll 4
    for(int k=0;k<ND;k++) acc = fmaf(xs[k], Wm[k*NIF+c], acc);
    wkey[tid] = acc;
  } else if (tid < 68){
    int c = 453 + (tid-64);
    float acc = bW[c];
    #pragma unroll 4
    for(int k=0;k<ND;k++) acc = fmaf(xs[k], Wm[k*NIF+c], acc);
    fgs[tid-64] = sigmoidf_(acc);
  }
  __syncthreads();
  int j = (role-2)*256 + tid;
  float fg0=fgs[0], fg1=fgs[1], fg2=fgs[2], fg3=fgs[3];
  float u0  = uv[b*NM+j];
  float wwo = ww_old[b*NM+j];
  float usage = u0 + (1.0f-u0)*wwo;
  float psi = (1.0f - fg0*rw_old[(b*NR+0)*NM+j])
            * (1.0f - fg1*rw_old[(b*NR+1)*NM+j])
            * (1.0f - fg2*rw_old[(b*NR+2)*NM+j])
            * (1.0f - fg3*rw_old[(b*NR+3)*NM+j]);
  usage *= psi;
  uu[b*NM+j] = DELTA + (1.0f-DELTA)*usage;
  float dot=0.0f, nrm=0.0f;
  const float4* mrow4 = (const float4*)(mem + ((size_t)b*NM + j)*NW);
  #pragma unroll 4
  for(int k=0;k<16;k++){
    float4 mv = mrow4[k];
    const float* wk = wkey + k*4;
    dot = fmaf(mv.x,wk[0],dot); dot = fmaf(mv.y,wk[1],dot);
    dot = fmaf(mv.z,wk[2],dot); dot = fmaf(mv.w,wk[3],dot);
    nrm = fmaf(mv.x,mv.x,nrm); nrm = fmaf(mv.y,mv.y,nrm);
    nrm = fmaf(mv.z,mv.z,nrm); nrm = fmaf(mv.w,mv.w,nrm);
  }
  wcd[b*NM+j]=dot; wcn[b*NM+j]=nrm;
}

// ---------------- K2: softmax + bitonic sort + cumprod + new_write_w (also zeroes sPK) ----------------
__global__ __launch_bounds__(1024) void k_write2(
    const float* __restrict__ iface, const float* __restrict__ uu,
    const float* __restrict__ wcd, const float* __restrict__ wcn,
    float* __restrict__ wwp, float* __restrict__ sPK){
  int b = blockIdx.x; int tid = threadIdx.x;
  int lane = tid & 63, wv = tid >> 6;
  __shared__ float wkey[NW];
  __shared__ ull skA[NM];
  __shared__ ull skB[NM];
  __shared__ float fb2[NM];
  __shared__ float red[17];
  __shared__ float s_wp[16], s_wp2[16];
  const float* ifb = iface + b*NIF;
  if (tid < NW) wkey[tid] = ifb[260+tid];
  if (tid < 16) sPK[b*16+tid] = 0.0f;
  __syncthreads();
  float sw = softplusf_(1.0f + fmaxf(ifb[324],0.0f));
  float ag = sigmoidf_(ifb[457]);
  float wg = sigmoidf_(ifb[458]);
  float kn=0.0f;
  for(int k=0;k<NW;k++){ float t=wkey[k]; kn += t*t; }
  kn = sqrtf(kn);
  float logit = sw * wcd[b*NM+tid] / ((sqrtf(wcn[b*NM+tid])+DELTA)*(kn+DELTA));
  float m1 = waveMax(logit); if(lane==0) red[wv]=m1; __syncthreads();
  if(tid==0){ float mm=red[0]; for(int i=1;i<16;i++) mm=fmaxf(mm,red[i]); red[16]=mm; } __syncthreads();
  float e = expf(logit - red[16]);
  float s1 = waveSum(e); if(lane==0) red[wv]=s1; __syncthreads();
  if(tid==0){ float ss=0; for(int i=0;i<16;i++) ss+=red[i]; red[16]=ss; } __syncthreads();
  float wcw = e/red[16];
  float u = uu[b*NM+tid];
  ull k = ((ull)__float_as_uint(u) << 32) | (unsigned)tid;
  bool useA = true;
  for (int k2=2; k2<=NM; k2<<=1){
    for (int jj=k2>>1; jj>0; jj>>=1){
      ull p;
      if (jj >= 64){
        ull* buf = useA ? skA : skB;
        buf[tid] = k;
        __syncthreads();
        p = buf[tid^jj];
        useA = !useA;
      } else {
        p = shflxor64(k, jj);
      }
      bool lower = (tid & jj) == 0;
      bool asc   = (tid & k2) == 0;
      bool takeMin = (lower == asc);
      k = takeMin ? (k<p ? k : p) : (k>p ? k : p);
    }
  }
  float su = __uint_as_float((unsigned)(k>>32));
  int phi  = (int)(k & 0xffffffffu);
  float sc = su;
  #pragma unroll
  for (int off=1; off<64; off<<=1){
    float t = __shfl_up(sc, off, 64);
    if (lane >= off) sc *= t;
  }
  if (lane==63) s_wp[wv] = sc;
  __syncthreads();
  if (tid==0){
    float p=1.0f;
    for (int w=0;w<16;w++){ float t=s_wp[w]; s_wp2[w]=p; p*=t; }
  }
  __syncthreads();
  float P = sc * s_wp2[wv];
  float salloc = (1.0f - su)*P;
  fb2[phi] = salloc;
  __syncthreads();
  float alloc = fb2[tid];
  wwp[b*NM+tid] = wg*(ag*alloc + (1.0f-ag)*wcw);
}

// ---------------- K3: fused link8 (byte-identical path) + rdots (ry==4 blocks) ----------------
// grid (4,5,NB). ry<4: round-11/15 k_link8 exactly (measured 82us, 39.6KB LDS -> 4 blocks/CU).
// ry==4: rdots2 body with its small tables ALIASED into s_L4 (no extra static LDS, occupancy
// unchanged). rdots blocks interleave per-b and fill link's stall bubbles; both depend only
// on wwp + inputs, so fusion is dependency-safe. (Round-14 lesson: fusion was fine, the link
// restructure was the regression — so link8 body is untouched here.)
__global__ __launch_bounds__(256) void k_linkdots(
    const float* __restrict__ link, const float* __restrict__ rw,
    const float* __restrict__ wwp,
    float4* __restrict__ RFp, float* __restrict__ C2p, float* __restrict__ C3p,
    float* __restrict__ ldiag,
    const float* __restrict__ iface, const float* __restrict__ mem,
    const float* __restrict__ prec, const float* __restrict__ rw_old,
    float* __restrict__ ce, float* __restrict__ sPK){
  int tid = threadIdx.x, lane = tid&63, wv = tid>>6;
  int b = blockIdx.z;
  __shared__ float4 s_L4[32*64];   // 32KB
  __shared__ float4 s_gcol4[256];  // 4KB
  __shared__ float  s_mwc[256];    // 1KB
  __shared__ float4 s_grow4[32];
  __shared__ float  s_wwr[32];
  __shared__ float4 s_rfp4[128];

  if (blockIdx.y == 4){
    // ===== rdots path (tables aliased into s_L4's LDS) =====
    float* base = (float*)s_L4;
    float* keys = base;            // [NR][NW] = 256
    float* er   = base + 256;      // 64
    float* wvec = base + 320;      // 64
    float* sk   = base + 384;      // 4
    float* red  = base + 392;      // [4][12] = 48
    int jt = blockIdx.x;
    const float* ifb = iface + b*NIF;
    { int r=tid>>6, kk=tid&63; keys[r*NW+kk] = ifb[r*NW+kk]; }
    if (tid < 64) er[tid] = sigmoidf_(ifb[325+tid]);
    else if (tid < 128) wvec[tid-64] = ifb[389+tid-64];
    else if (tid < 132){
      int r = tid-128;
      float knv=0;
      for(int k=0;k<NW;k++){ float t=ifb[r*NW+k]; knv += t*t; }
      sk[r] = softplusf_(1.0f + fmaxf(ifb[256+r],0.0f)) / (sqrtf(knv)+DELTA);
    }
    __syncthreads();
    int j = jt*256 + tid;
    float wwj = wwp[b*NM+j];
    float pj  = prec[b*NM+j];
    const float* mrow = mem + ((size_t)b*NM+j)*NW;
    float dt[NR]={0,0,0,0}; float nrm=0.0f;
    for(int k=0;k<NW;k++){
      float nmv = fmaf(mrow[k], (1.0f - wwj*er[k]), wwj*wvec[k]);
      nrm = fmaf(nmv,nmv,nrm);
      #pragma unroll
      for(int r=0;r<NR;r++) dt[r] = fmaf(nmv, keys[r*NW+k], dt[r]);
    }
    float inv = 1.0f/(sqrtf(nrm)+DELTA);
    float v12[12];
    #pragma unroll
    for(int r=0;r<NR;r++){
      float e = expf(sk[r]*dt[r]*inv);
      ce[(b*NR+r)*NM + j] = e;
      float rwv = rw_old[(b*NR+r)*NM+j];
      v12[r]   = pj*rwv;
      v12[4+r] = wwj*rwv;
      v12[8+r] = e;
    }
    #pragma unroll
    for(int q=0;q<12;q++){
      float s = waveSum(v12[q]);
      if (lane==0) red[wv*12+q] = s;
    }
    __syncthreads();
    if (tid < 12){
      float s = red[0*12+tid]+red[1*12+tid]+red[2*12+tid]+red[3*12+tid];
      atomicAdd(&sPK[b*16+tid], s);
    }
    return;
  }

  // ===== link path (byte-identical to round-15 k_link8) =====
  int cx = blockIdx.x, ry = blockIdx.y;
  const float* Lb = link + ((size_t)b<<20);
  int colbase = cx*256, rowbase = ry*256;
  {
    float g0 = rw[(b*NR+0)*NM + colbase + tid];
    float g1 = rw[(b*NR+1)*NM + colbase + tid];
    float g2 = rw[(b*NR+2)*NM + colbase + tid];
    float g3 = rw[(b*NR+3)*NM + colbase + tid];
    s_gcol4[tid] = make_float4(g0,g1,g2,g3);
    s_mwc[tid] = 1.0f - wwp[b*NM + colbase + tid];
  }
  float c2a[NR][4], c3a[NR][4];
  #pragma unroll
  for(int r=0;r<NR;r++){
    #pragma unroll
    for(int e=0;e<4;e++){ c2a[r][e]=0.0f; c3a[r][e]=0.0f; }
  }
  for (int ch=0; ch<8; ++ch){
    int rb = rowbase + ch*32;
    if (tid < 128) ((float*)s_grow4)[tid] = rw[(b*NR+(tid&3))*NM + rb + (tid>>2)];
    if (tid < 32)  s_wwr[tid] = wwp[b*NM + rb + tid];
    #pragma unroll
    for (int jq=0;jq<8;jq++){
      int rl = wv + 4*jq;
      float4 lv = *(const float4*)(Lb + (size_t)(rb+rl)*NM + colbase + lane*4);
      s_L4[rl*64 + (lane ^ ((rl>>1)&7))] = lv;
    }
    __syncthreads();
    if (cx == ry && tid < 32){
      int coff = ch*32 + tid;
      float4 v = s_L4[tid*64 + ((coff>>2) ^ ((tid>>1)&7))];
      float d = (coff&1) ? ((coff&2)? v.w : v.y) : ((coff&2)? v.z : v.x);
      ldiag[b*NM + rb + tid] = d;
    }
    {
      int i5 = lane & 15, cg = lane >> 4;
      int rl0 = 2*i5;
      int sz = i5 & 7;
      float wwj0 = s_wwr[rl0], wwj1 = s_wwr[rl0+1];
      float rf0[4] = {0,0,0,0}, rf1[4] = {0,0,0,0};
      #pragma unroll
      for (int q=0;q<4;q++){
        int cq = wv*16 + cg*4 + q;
        float4 mw  = ((const float4*)s_mwc)[cq];
        float4 lv0 = s_L4[rl0*64 + (cq ^ sz)];
        float4 lv1 = s_L4[(rl0+1)*64 + (cq ^ sz)];
        float le0[4]={lv0.x,lv0.y,lv0.z,lv0.w};
        float le1[4]={lv1.x,lv1.y,lv1.z,lv1.w};
        float mv[4]={mw.x,mw.y,mw.z,mw.w};
        #pragma unroll
        for (int e=0;e<4;e++){
          float4 gv = s_gcol4[cq*4+e];
          float lt0 = le0[e]*(mv[e]-wwj0);
          float lt1 = le1[e]*(mv[e]-wwj1);
          rf0[0]=fmaf(lt0,gv.x,rf0[0]); rf0[1]=fmaf(lt0,gv.y,rf0[1]);
          rf0[2]=fmaf(lt0,gv.z,rf0[2]); rf0[3]=fmaf(lt0,gv.w,rf0[3]);
          rf1[0]=fmaf(lt1,gv.x,rf1[0]); rf1[1]=fmaf(lt1,gv.y,rf1[1]);
          rf1[2]=fmaf(lt1,gv.z,rf1[2]); rf1[3]=fmaf(lt1,gv.w,rf1[3]);
        }
      }
      #pragma unroll
      for (int r=0;r<NR;r++){
        rf0[r] += __shfl_xor(rf0[r], 16, 64);
        rf0[r] += __shfl_xor(rf0[r], 32, 64);
        rf1[r] += __shfl_xor(rf1[r], 16, 64);
        rf1[r] += __shfl_xor(rf1[r], 32, 64);
      }
      if (cg == 0){
        s_rfp4[wv*32 + rl0]     = make_float4(rf0[0],rf0[1],rf0[2],rf0[3]);
        s_rfp4[wv*32 + rl0 + 1] = make_float4(rf1[0],rf1[1],rf1[2],rf1[3]);
      }
    }
    #pragma unroll 2
    for (int ri=0; ri<8; ri++){
      int row = wv*8 + ri;
      float4 lv = s_L4[row*64 + (lane ^ ((row>>1)&7))];
      float4 gg = s_grow4[row];
      float wwr = s_wwr[row];
      float le[4] = {lv.x,lv.y,lv.z,lv.w};
      float ggv[4] = {gg.x,gg.y,gg.z,gg.w};
      float ggw[4];
      #pragma unroll
      for (int r=0;r<NR;r++) ggw[r] = ggv[r]*wwr;
      #pragma unroll
      for (int e=0;e<4;e++){
        #pragma unroll
        for (int r=0;r<NR;r++){
          c2a[r][e] = fmaf(le[e], ggv[r], c2a[r][e]);
          c3a[r][e] = fmaf(le[e], ggw[r], c3a[r][e]);
        }
      }
    }
    __syncthreads();
    if (tid < 128){
      int row = tid>>2, r = tid&3;
      float s = ((const float*)&s_rfp4[0*32+row])[r] + ((const float*)&s_rfp4[1*32+row])[r]
              + ((const float*)&s_rfp4[2*32+row])[r] + ((const float*)&s_rfp4[3*32+row])[r];
      ((float*)RFp)[((size_t)cx<<18) + (b*NM + rb + row)*4 + r] = s;
    }
    __syncthreads();
  }
  float4* s_comb = s_L4;
  #pragma unroll
  for (int r=0;r<NR;r++){
    s_comb[tid*8 + r]     = make_float4(c2a[r][0],c2a[r][1],c2a[r][2],c2a[r][3]);
    s_comb[tid*8 + 4 + r] = make_float4(c3a[r][0],c3a[r][1],c3a[r][2],c3a[r][3]);
  }
  __syncthreads();
  for (int t=tid; t<512; t+=256){
    int lc = t>>3, q = t&7;
    float4 a = s_comb[(0*64+lc)*8+q];
    float4 bb= s_comb[(1*64+lc)*8+q];
    float4 c = s_comb[(2*64+lc)*8+q];
    float4 d = s_comb[(3*64+lc)*8+q];
    float4 s = make_float4(a.x+bb.x+c.x+d.x, a.y+bb.y+c.y+d.y, a.z+bb.z+c.z+d.z, a.w+bb.w+c.w+d.w);
    float* dst = (q<4) ? &C2p[((size_t)ry<<18) + (b*NR+q)*NM + colbase + lc*4]
                       : &C3p[((size_t)ry<<18) + (b*NR+(q-4))*NM + colbase + lc*4];
    *(float4*)dst = s;
  }
}

// ---------------- K4: fused finalize (nrw inline) + read_vectors partial matmul ----------------
__global__ __launch_bounds__(256) void k_readf(
    const float* __restrict__ iface, const float* __restrict__ mem,
    const float* __restrict__ wwp, const float* __restrict__ prec,
    const float* __restrict__ rw_old, const float* __restrict__ ldiag,
    const float4* __restrict__ RFp4, const float* __restrict__ C2p, const float* __restrict__ C3p,
    const float* __restrict__ ce, const float* __restrict__ sPK,
    float* __restrict__ out){
  int jt = blockIdx.x, b = blockIdx.y;
  int tid = threadIdx.x, lane = tid&63, wv = tid>>6;
  __shared__ float s_nrw[NR][256];
  __shared__ float s_ww[256];
  __shared__ float s_er[NW], s_wv[NW];
  __shared__ float s_acc[4][NR][NW];
  __shared__ float rm[NR][3];
  __shared__ float s_sc[16];
  const float* ifb = iface + b*NIF;
  if (tid == 0){
    for(int mo=0;mo<3;mo++){
      float x0=ifb[458+0*3+mo], x1=ifb[458+1*3+mo], x2=ifb[458+2*3+mo], x3=ifb[458+3*3+mo];
      float mx = fmaxf(fmaxf(x0,x1),fmaxf(x2,x3));
      float e0=expf(x0-mx),e1=expf(x1-mx),e2=expf(x2-mx),e3=expf(x3-mx);
      float s=e0+e1+e2+e3;
      rm[0][mo]=e0/s; rm[1][mo]=e1/s; rm[2][mo]=e2/s; rm[3][mo]=e3/s;
    }
  }
  if (tid >= 64 && tid < 80)  s_sc[tid-64] = sPK[b*16 + (tid-64)];
  if (tid >= 128 && tid < 192) s_er[tid-128] = sigmoidf_(ifb[325+tid-128]);
  if (tid >= 192)              s_wv[tid-192] = ifb[389+tid-192];
  int j0 = jt*256;
  int j = j0 + tid;
  float wwj = wwp[b*NM+j];
  s_ww[tid] = wwj;
  __syncthreads();
  float pj  = prec[b*NM+j];
  float Ljj = ldiag[b*NM+j];
  float4 Fa = RFp4[(0<<16) + b*NM + j];
  float4 Fb = RFp4[(1<<16) + b*NM + j];
  float4 Fc = RFp4[(2<<16) + b*NM + j];
  float4 Fd = RFp4[(3<<16) + b*NM + j];
  float Fr[4] = {Fa.x+Fb.x+Fc.x+Fd.x, Fa.y+Fb.y+Fc.y+Fd.y,
                 Fa.z+Fb.z+Fc.z+Fd.z, Fa.w+Fb.w+Fc.w+Fd.w};
  #pragma unroll
  for(int r=0;r<NR;r++){
    int idx = (b*NR+r)*NM + j;
    float cc2 = C2p[idx] + C2p[262144+idx] + C2p[524288+idx] + C2p[786432+idx];
    float cc3 = C3p[idx] + C3p[262144+idx] + C3p[524288+idx] + C3p[786432+idx];
    float grj = rw_old[idx];
    float cwv = ce[idx] / s_sc[8+r];
    float fwd = Fr[r] - Ljj*grj*(1.0f-2.0f*wwj) + wwj*(s_sc[r] - pj*grj);
    float bwd = (cc2 - cc3) - Ljj*grj*(1.0f-wwj) - wwj*(cc2 - Ljj*grj) + pj*(s_sc[4+r] - wwj*grj);
    s_nrw[r][tid] = rm[r][0]*bwd + rm[r][1]*fwd + rm[r][2]*cwv;
  }
  __syncthreads();
  int w = lane;
  float erw = s_er[w], wvw = s_wv[w];
  float acc[NR]={0,0,0,0};
  for(int jj=0;jj<64;jj++){
    int jl = wv*64+jj;
    float wwr = s_ww[jl];
    float nmv = fmaf(mem[((size_t)b*NM + j0+jl)*NW + w], (1.0f - wwr*erw), wwr*wvw);
    #pragma unroll
    for(int r=0;r<NR;r++) acc[r] = fmaf(s_nrw[r][jl], nmv, acc[r]);
  }
  #pragma unroll
  for(int r=0;r<NR;r++) s_acc[wv][r][w] = acc[r];
  __syncthreads();
  {
    int r = tid>>6, k = tid&63;
    float s = s_acc[0][r][k]+s_acc[1][r][k]+s_acc[2][r][k]+s_acc[3][r][k];
    atomicAdd(&out[b*NR*NW + r*NW + k], s);
  }
}

extern "C" void kernel_launch(void* const* d_in, const int* in_sizes, int n_in,
                              void* d_out, int out_size, void* d_ws, size_t ws_size,
                              hipStream_t stream) {
  (void)in_sizes; (void)n_in; (void)out_size; (void)ws_size;
  const float* xi   = (const float*)d_in[0];
  const float* Wm   = (const float*)d_in[1];
  const float* bW   = (const float*)d_in[2];
  const float* mem  = (const float*)d_in[3];
  const float* link = (const float*)d_in[4];
  const float* prec = (const float*)d_in[5];
  const float* rw   = (const float*)d_in[6];
  const float* wwo  = (const float*)d_in[7];
  const float* uv   = (const float*)d_in[8];
  float* out = (float*)d_out;
  float* ws  = (float*)d_ws;
  float* iface = ws;                  // 30208
  float* wwp   = ws + 30208;          // 65536
  float* uu    = ws + 95744;          // 65536
  float* wcd   = ws + 161280;         // 65536
  float* wcn   = ws + 226816;         // 65536
  float* ce    = ws + 292352;         // 262144 = [b][4][1024]
  float* ldiag = ws + 554496;         // 65536
  float* sPK   = ws + 620032;         // 1024 = [b][16]
  float* RFp   = ws + 621056;         // 4*262144 (float4-aligned)
  float* C2p   = ws + 1669632;        // 4*262144
  float* C3p   = ws + 2718208;        // 4*262144
  k_ifw  <<<dim3(6,NB), 256, 0, stream>>>(xi, Wm, bW, mem, rw, wwo, uv,
                                          iface, (float4*)out, uu, wcd, wcn);
  k_write2<<<NB, 1024, 0, stream>>>(iface, uu, wcd, wcn, wwp, sPK);
  k_linkdots<<<dim3(4,5,NB), 256, 0, stream>>>(link, rw, wwp, (float4*)RFp, C2p, C3p, ldiag,
                                               iface, mem, prec, rw, ce, sPK);
  k_readf<<<dim3(4,NB), 256, 0, stream>>>(iface, mem, wwp, prec, rw, ldiag,
                                          (const float4*)RFp, C2p, C3p, ce, sPK, out);
}

// Round 17
// 148.844 us; speedup vs baseline: 1.0302x; 1.0302x over previous
//
#include <hip/hip_runtime.h>

#define DELTA 1e-6f

// sizes: b=64, m=1024, w=64, r=4, d=512, iface=471
#define NB 64
#define NM 1024
#define NW 64
#define NR 4
#define ND 512
#define NIF 471

typedef unsigned long long ull;

__device__ __forceinline__ float sigmoidf_(float x){ return 1.0f/(1.0f+expf(-x)); }
__device__ __forceinline__ float softplusf_(float x){ return fmaxf(x,0.0f) + log1pf(expf(-fabsf(x))); }

__device__ __forceinline__ float waveSum(float v){
  #pragma unroll
  for(int o=32;o>0;o>>=1) v += __shfl_down(v,o,64);
  return v;
}
__device__ __forceinline__ float waveMax(float v){
  #pragma unroll
  for(int o=32;o>0;o>>=1) v = fmaxf(v, __shfl_down(v,o,64));
  return v;
}
__device__ __forceinline__ ull shflxor64(ull k, int m){
  unsigned lo = (unsigned)(k & 0xffffffffu), hi = (unsigned)(k>>32);
  lo = (unsigned)__shfl_xor((int)lo, m, 64);
  hi = (unsigned)__shfl_xor((int)hi, m, 64);
  return ((ull)hi<<32)|lo;
}

// ---------------- K1: iface = xi @ W + bW (128 blocks); half==0 blocks also zero `out` ----------------
__global__ __launch_bounds__(256) void k_iface(const float* __restrict__ xi,
                                               const float* __restrict__ Wm,
                                               const float* __restrict__ bW,
                                               float* __restrict__ iface,
                                               float4* __restrict__ out4){
  int b = blockIdx.x, half = blockIdx.y;
  __shared__ float xs[ND];
  if (half == 0 && threadIdx.x < 64) out4[b*64 + threadIdx.x] = make_float4(0.f,0.f,0.f,0.f);
  for(int k=threadIdx.x;k<ND;k+=256) xs[k]=xi[b*ND+k];
  __syncthreads();
  int c = half*236 + threadIdx.x;
  int cend = half ? NIF : 236;
  if (c < cend){
    float acc = bW[c];
    #pragma unroll 4
    for(int k=0;k<ND;k++) acc = fmaf(xs[k], Wm[k*NIF+c], acc);
    iface[b*NIF+c]=acc;
  }
}

// ---------------- K1b: full-GPU pass over mem for write-content dot/nrm + usage ----------------
__global__ __launch_bounds__(256) void k_wcos(
    const float* __restrict__ iface, const float* __restrict__ mem,
    const float* __restrict__ rw_old, const float* __restrict__ ww_old,
    const float* __restrict__ uv,
    float* __restrict__ uu, float* __restrict__ wcd, float* __restrict__ wcn){
  int b = blockIdx.y;
  int j = blockIdx.x*256 + threadIdx.x;
  __shared__ float wkey[NW];
  const float* ifb = iface + b*NIF;
  if (threadIdx.x < NW) wkey[threadIdx.x] = ifb[260+threadIdx.x];
  __syncthreads();
  float fg0=sigmoidf_(ifb[453]), fg1=sigmoidf_(ifb[454]);
  float fg2=sigmoidf_(ifb[455]), fg3=sigmoidf_(ifb[456]);
  float u0  = uv[b*NM+j];
  float wwo = ww_old[b*NM+j];
  float usage = u0 + (1.0f-u0)*wwo;
  float psi = (1.0f - fg0*rw_old[(b*NR+0)*NM+j])
            * (1.0f - fg1*rw_old[(b*NR+1)*NM+j])
            * (1.0f - fg2*rw_old[(b*NR+2)*NM+j])
            * (1.0f - fg3*rw_old[(b*NR+3)*NM+j]);
  usage *= psi;
  uu[b*NM+j] = DELTA + (1.0f-DELTA)*usage;
  float dot=0.0f, nrm=0.0f;
  const float4* mrow4 = (const float4*)(mem + ((size_t)b*NM + j)*NW);
  #pragma unroll 4
  for(int k=0;k<16;k++){
    float4 mv = mrow4[k];
    const float* wk = wkey + k*4;
    dot = fmaf(mv.x,wk[0],dot); dot = fmaf(mv.y,wk[1],dot);
    dot = fmaf(mv.z,wk[2],dot); dot = fmaf(mv.w,wk[3],dot);
    nrm = fmaf(mv.x,mv.x,nrm); nrm = fmaf(mv.y,mv.y,nrm);
    nrm = fmaf(mv.z,mv.z,nrm); nrm = fmaf(mv.w,mv.w,nrm);
  }
  wcd[b*NM+j]=dot; wcn[b*NM+j]=nrm;
}

// ---------------- K2: softmax + bitonic sort + cumprod + new_write_w (also zeroes sPK) ----------------
__global__ __launch_bounds__(1024) void k_write2(
    const float* __restrict__ iface, const float* __restrict__ uu,
    const float* __restrict__ wcd, const float* __restrict__ wcn,
    float* __restrict__ wwp, float* __restrict__ sPK){
  int b = blockIdx.x; int tid = threadIdx.x;
  int lane = tid & 63, wv = tid >> 6;
  __shared__ float wkey[NW];
  __shared__ ull skA[NM];
  __shared__ ull skB[NM];
  __shared__ float fb2[NM];
  __shared__ float red[17];
  __shared__ float s_wp[16], s_wp2[16];
  const float* ifb = iface + b*NIF;
  if (tid < NW) wkey[tid] = ifb[260+tid];
  if (tid < 16) sPK[b*16+tid] = 0.0f;   // zero the rdots2 atomic accumulators
  __syncthreads();
  float sw = softplusf_(1.0f + fmaxf(ifb[324],0.0f));
  float ag = sigmoidf_(ifb[457]);
  float wg = sigmoidf_(ifb[458]);
  float kn=0.0f;
  for(int k=0;k<NW;k++){ float t=wkey[k]; kn += t*t; }
  kn = sqrtf(kn);
  float logit = sw * wcd[b*NM+tid] / ((sqrtf(wcn[b*NM+tid])+DELTA)*(kn+DELTA));
  float m1 = waveMax(logit); if(lane==0) red[wv]=m1; __syncthreads();
  if(tid==0){ float mm=red[0]; for(int i=1;i<16;i++) mm=fmaxf(mm,red[i]); red[16]=mm; } __syncthreads();
  float e = expf(logit - red[16]);
  float s1 = waveSum(e); if(lane==0) red[wv]=s1; __syncthreads();
  if(tid==0){ float ss=0; for(int i=0;i<16;i++) ss+=red[i]; red[16]=ss; } __syncthreads();
  float wcw = e/red[16];
  float u = uu[b*NM+tid];
  ull k = ((ull)__float_as_uint(u) << 32) | (unsigned)tid;
  bool useA = true;
  for (int k2=2; k2<=NM; k2<<=1){
    for (int jj=k2>>1; jj>0; jj>>=1){
      ull p;
      if (jj >= 64){
        ull* buf = useA ? skA : skB;
        buf[tid] = k;
        __syncthreads();
        p = buf[tid^jj];
        useA = !useA;
      } else {
        p = shflxor64(k, jj);
      }
      bool lower = (tid & jj) == 0;
      bool asc   = (tid & k2) == 0;
      bool takeMin = (lower == asc);
      k = takeMin ? (k<p ? k : p) : (k>p ? k : p);
    }
  }
  float su = __uint_as_float((unsigned)(k>>32));
  int phi  = (int)(k & 0xffffffffu);
  float sc = su;
  #pragma unroll
  for (int off=1; off<64; off<<=1){
    float t = __shfl_up(sc, off, 64);
    if (lane >= off) sc *= t;
  }
  if (lane==63) s_wp[wv] = sc;
  __syncthreads();
  if (tid==0){
    float p=1.0f;
    for (int w=0;w<16;w++){ float t=s_wp[w]; s_wp2[w]=p; p*=t; }
  }
  __syncthreads();
  float P = sc * s_wp2[wv];
  float salloc = (1.0f - su)*P;
  fb2[phi] = salloc;
  __syncthreads();
  float alloc = fb2[tid];
  wwp[b*NM+tid] = wg*(ag*alloc + (1.0f-ag)*wcw);
}

// ---------------- K3: one streaming pass over L — EXACT round-11 k_link8 (measured 82us) ----------------
__global__ __launch_bounds__(256) void k_link8(
    const float* __restrict__ link, const float* __restrict__ rw,
    const float* __restrict__ wwp,
    float4* __restrict__ RFp, float* __restrict__ C2p, float* __restrict__ C3p,
    float* __restrict__ ldiag){
  int cx = blockIdx.x, ry = blockIdx.y, b = blockIdx.z;
  int tid = threadIdx.x, lane = tid&63, wv = tid>>6;
  __shared__ float4 s_L4[32*64];   // 32KB
  __shared__ float4 s_gcol4[256];  // 4KB {g0..g3} per col
  __shared__ float  s_mwc[256];    // 1KB: 1-ww[col]
  __shared__ float4 s_grow4[32];
  __shared__ float  s_wwr[32];
  __shared__ float4 s_rfp4[128];
  const float* Lb = link + ((size_t)b<<20);
  int colbase = cx*256, rowbase = ry*256;
  {
    float g0 = rw[(b*NR+0)*NM + colbase + tid];
    float g1 = rw[(b*NR+1)*NM + colbase + tid];
    float g2 = rw[(b*NR+2)*NM + colbase + tid];
    float g3 = rw[(b*NR+3)*NM + colbase + tid];
    s_gcol4[tid] = make_float4(g0,g1,g2,g3);
    s_mwc[tid] = 1.0f - wwp[b*NM + colbase + tid];
  }
  float c2a[NR][4], c3a[NR][4];
  #pragma unroll
  for(int r=0;r<NR;r++){
    #pragma unroll
    for(int e=0;e<4;e++){ c2a[r][e]=0.0f; c3a[r][e]=0.0f; }
  }
  for (int ch=0; ch<8; ++ch){
    int rb = rowbase + ch*32;
    if (tid < 128) ((float*)s_grow4)[tid] = rw[(b*NR+(tid&3))*NM + rb + (tid>>2)];
    if (tid < 32)  s_wwr[tid] = wwp[b*NM + rb + tid];
    #pragma unroll
    for (int jq=0;jq<8;jq++){
      int rl = wv + 4*jq;
      float4 lv = *(const float4*)(Lb + (size_t)(rb+rl)*NM + colbase + lane*4);
      s_L4[rl*64 + (lane ^ ((rl>>1)&7))] = lv;
    }
    __syncthreads();
    if (cx == ry && tid < 32){
      int coff = ch*32 + tid;
      float4 v = s_L4[tid*64 + ((coff>>2) ^ ((tid>>1)&7))];
      float d = (coff&1) ? ((coff&2)? v.w : v.y) : ((coff&2)? v.z : v.x);
      ldiag[b*NM + rb + tid] = d;
    }
    {
      int i5 = lane & 15, cg = lane >> 4;
      int rl0 = 2*i5;
      int sz = i5 & 7;
      float wwj0 = s_wwr[rl0], wwj1 = s_wwr[rl0+1];
      float rf0[4] = {0,0,0,0}, rf1[4] = {0,0,0,0};
      #pragma unroll
      for (int q=0;q<4;q++){
        int cq = wv*16 + cg*4 + q;
        float4 mw  = ((const float4*)s_mwc)[cq];
        float4 lv0 = s_L4[rl0*64 + (cq ^ sz)];
        float4 lv1 = s_L4[(rl0+1)*64 + (cq ^ sz)];
        float le0[4]={lv0.x,lv0.y,lv0.z,lv0.w};
        float le1[4]={lv1.x,lv1.y,lv1.z,lv1.w};
        float mv[4]={mw.x,mw.y,mw.z,mw.w};
        #pragma unroll
        for (int e=0;e<4;e++){
          float4 gv = s_gcol4[cq*4+e];
          float lt0 = le0[e]*(mv[e]-wwj0);
          float lt1 = le1[e]*(mv[e]-wwj1);
          rf0[0]=fmaf(lt0,gv.x,rf0[0]); rf0[1]=fmaf(lt0,gv.y,rf0[1]);
          rf0[2]=fmaf(lt0,gv.z,rf0[2]); rf0[3]=fmaf(lt0,gv.w,rf0[3]);
          rf1[0]=fmaf(lt1,gv.x,rf1[0]); rf1[1]=fmaf(lt1,gv.y,rf1[1]);
          rf1[2]=fmaf(lt1,gv.z,rf1[2]); rf1[3]=fmaf(lt1,gv.w,rf1[3]);
        }
      }
      #pragma unroll
      for (int r=0;r<NR;r++){
        rf0[r] += __shfl_xor(rf0[r], 16, 64);
        rf0[r] += __shfl_xor(rf0[r], 32, 64);
        rf1[r] += __shfl_xor(rf1[r], 16, 64);
        rf1[r] += __shfl_xor(rf1[r], 32, 64);
      }
      if (cg == 0){
        s_rfp4[wv*32 + rl0]     = make_float4(rf0[0],rf0[1],rf0[2],rf0[3]);
        s_rfp4[wv*32 + rl0 + 1] = make_float4(rf1[0],rf1[1],rf1[2],rf1[3]);
      }
    }
    #pragma unroll 2
    for (int ri=0; ri<8; ri++){
      int row = wv*8 + ri;
      float4 lv = s_L4[row*64 + (lane ^ ((row>>1)&7))];
      float4 gg = s_grow4[row];
      float wwr = s_wwr[row];
      float le[4] = {lv.x,lv.y,lv.z,lv.w};
      float ggv[4] = {gg.x,gg.y,gg.z,gg.w};
      float ggw[4];
      #pragma unroll
      for (int r=0;r<NR;r++) ggw[r] = ggv[r]*wwr;
      #pragma unroll
      for (int e=0;e<4;e++){
        #pragma unroll
        for (int r=0;r<NR;r++){
          c2a[r][e] = fmaf(le[e], ggv[r], c2a[r][e]);
          c3a[r][e] = fmaf(le[e], ggw[r], c3a[r][e]);
        }
      }
    }
    __syncthreads();
    if (tid < 128){
      int row = tid>>2, r = tid&3;
      float s = ((const float*)&s_rfp4[0*32+row])[r] + ((const float*)&s_rfp4[1*32+row])[r]
              + ((const float*)&s_rfp4[2*32+row])[r] + ((const float*)&s_rfp4[3*32+row])[r];
      ((float*)RFp)[((size_t)cx<<18) + (b*NM + rb + row)*4 + r] = s;
    }
    __syncthreads();
  }
  float4* s_comb = s_L4;
  #pragma unroll
  for (int r=0;r<NR;r++){
    s_comb[tid*8 + r]     = make_float4(c2a[r][0],c2a[r][1],c2a[r][2],c2a[r][3]);
    s_comb[tid*8 + 4 + r] = make_float4(c3a[r][0],c3a[r][1],c3a[r][2],c3a[r][3]);
  }
  __syncthreads();
  for (int t=tid; t<512; t+=256){
    int lc = t>>3, q = t&7;
    float4 a = s_comb[(0*64+lc)*8+q];
    float4 bb= s_comb[(1*64+lc)*8+q];
    float4 c = s_comb[(2*64+lc)*8+q];
    float4 d = s_comb[(3*64+lc)*8+q];
    float4 s = make_float4(a.x+bb.x+c.x+d.x, a.y+bb.y+c.y+d.y, a.z+bb.z+c.z+d.z, a.w+bb.w+c.w+d.w);
    float* dst = (q<4) ? &C2p[((size_t)ry<<18) + (b*NR+q)*NM + colbase + lc*4]
                       : &C3p[((size_t)ry<<18) + (b*NR+(q-4))*NM + colbase + lc*4];
    *(float4*)dst = s;
  }
}

// ---------------- K4a: mem pass -> ce = exp(read logit) + block partials of Pr/Kr/sumexp ----------------
__global__ __launch_bounds__(256) void k_rdots2(
    const float* __restrict__ iface, const float* __restrict__ mem,
    const float* __restrict__ wwp, const float* __restrict__ prec,
    const float* __restrict__ rw_old,
    float* __restrict__ ce, float* __restrict__ sPK){
  int b = blockIdx.y, jt = blockIdx.x;
  int tid = threadIdx.x, lane = tid&63, wv = tid>>6;
  __shared__ float keys[NR][NW];
  __shared__ float er[NW], wvec[NW];
  __shared__ float sk[NR];
  __shared__ float red[4][12];
  const float* ifb = iface + b*NIF;
  { int r=tid>>6, kk=tid&63; keys[r][kk] = ifb[r*NW+kk]; }
  if (tid < 64) er[tid] = sigmoidf_(ifb[325+tid]);
  else if (tid < 128) wvec[tid-64] = ifb[389+tid-64];
  else if (tid < 132){
    int r = tid-128;
    float knv=0;
    for(int k=0;k<NW;k++){ float t=ifb[r*NW+k]; knv += t*t; }
    sk[r] = softplusf_(1.0f + fmaxf(ifb[256+r],0.0f)) / (sqrtf(knv)+DELTA);
  }
  __syncthreads();
  int j = jt*256 + tid;
  float wwj = wwp[b*NM+j];
  float pj  = prec[b*NM+j];
  const float* mrow = mem + ((size_t)b*NM+j)*NW;
  float dt[NR]={0,0,0,0}; float nrm=0.0f;
  for(int k=0;k<NW;k++){
    float nmv = fmaf(mrow[k], (1.0f - wwj*er[k]), wwj*wvec[k]);
    nrm = fmaf(nmv,nmv,nrm);
    #pragma unroll
    for(int r=0;r<NR;r++) dt[r] = fmaf(nmv, keys[r][k], dt[r]);
  }
  float inv = 1.0f/(sqrtf(nrm)+DELTA);
  float v12[12];
  #pragma unroll
  for(int r=0;r<NR;r++){
    float e = expf(sk[r]*dt[r]*inv);
    ce[(b*NR+r)*NM + j] = e;
    float rwv = rw_old[(b*NR+r)*NM+j];
    v12[r]   = pj*rwv;    // Pr partial
    v12[4+r] = wwj*rwv;   // Kr partial
    v12[8+r] = e;         // sum-exp partial
  }
  #pragma unroll
  for(int q=0;q<12;q++){
    float s = waveSum(v12[q]);
    if (lane==0) red[wv][q] = s;
  }
  __syncthreads();
  if (tid < 12){
    float s = red[0][tid]+red[1][tid]+red[2][tid]+red[3][tid];
    atomicAdd(&sPK[b*16+tid], s);
  }
}

// ---------------- K4b: fused finalize (nrw inline) + read_vectors partial matmul ----------------
__global__ __launch_bounds__(256) void k_readf(
    const float* __restrict__ iface, const float* __restrict__ mem,
    const float* __restrict__ wwp, const float* __restrict__ prec,
    const float* __restrict__ rw_old, const float* __restrict__ ldiag,
    const float4* __restrict__ RFp4, const float* __restrict__ C2p, const float* __restrict__ C3p,
    const float* __restrict__ ce, const float* __restrict__ sPK,
    float* __restrict__ out){
  int jt = blockIdx.x, b = blockIdx.y;
  int tid = threadIdx.x, lane = tid&63, wv = tid>>6;
  __shared__ float s_nrw[NR][256];
  __shared__ float s_ww[256];
  __shared__ float s_er[NW], s_wv[NW];
  __shared__ float s_acc[4][NR][NW];
  __shared__ float rm[NR][3];
  __shared__ float s_sc[16];   // [0..3]=Pr, [4..7]=Kr, [8..11]=sumexp
  const float* ifb = iface + b*NIF;
  if (tid == 0){
    for(int mo=0;mo<3;mo++){
      float x0=ifb[458+0*3+mo], x1=ifb[458+1*3+mo], x2=ifb[458+2*3+mo], x3=ifb[458+3*3+mo];
      float mx = fmaxf(fmaxf(x0,x1),fmaxf(x2,x3));
      float e0=expf(x0-mx),e1=expf(x1-mx),e2=expf(x2-mx),e3=expf(x3-mx);
      float s=e0+e1+e2+e3;
      rm[0][mo]=e0/s; rm[1][mo]=e1/s; rm[2][mo]=e2/s; rm[3][mo]=e3/s;
    }
  }
  if (tid >= 64 && tid < 80)  s_sc[tid-64] = sPK[b*16 + (tid-64)];
  if (tid >= 128 && tid < 192) s_er[tid-128] = sigmoidf_(ifb[325+tid-128]);
  if (tid >= 192)              s_wv[tid-192] = ifb[389+tid-192];
  int j0 = jt*256;
  int j = j0 + tid;
  float wwj = wwp[b*NM+j];
  s_ww[tid] = wwj;
  __syncthreads();
  float pj  = prec[b*NM+j];
  float Ljj = ldiag[b*NM+j];
  float4 Fa = RFp4[(0<<16) + b*NM + j];
  float4 Fb = RFp4[(1<<16) + b*NM + j];
  float4 Fc = RFp4[(2<<16) + b*NM + j];
  float4 Fd = RFp4[(3<<16) + b*NM + j];
  float Fr[4] = {Fa.x+Fb.x+Fc.x+Fd.x, Fa.y+Fb.y+Fc.y+Fd.y,
                 Fa.z+Fb.z+Fc.z+Fd.z, Fa.w+Fb.w+Fc.w+Fd.w};
  #pragma unroll
  for(int r=0;r<NR;r++){
    int idx = (b*NR+r)*NM + j;
    float cc2 = C2p[idx] + C2p[262144+idx] + C2p[524288+idx] + C2p[786432+idx];
    float cc3 = C3p[idx] + C3p[262144+idx] + C3p[524288+idx] + C3p[786432+idx];
    float grj = rw_old[idx];
    float cwv = ce[idx] / s_sc[8+r];
    float fwd = Fr[r] - Ljj*grj*(1.0f-2.0f*wwj) + wwj*(s_sc[r] - pj*grj);
    float bwd = (cc2 - cc3) - Ljj*grj*(1.0f-wwj) - wwj*(cc2 - Ljj*grj) + pj*(s_sc[4+r] - wwj*grj);
    s_nrw[r][tid] = rm[r][0]*bwd + rm[r][1]*fwd + rm[r][2]*cwv;
  }
  __syncthreads();
  int w = lane;
  float erw = s_er[w], wvw = s_wv[w];
  float acc[NR]={0,0,0,0};
  for(int jj=0;jj<64;jj++){
    int jl = wv*64+jj;
    float wwr = s_ww[jl];
    float nmv = fmaf(mem[((size_t)b*NM + j0+jl)*NW + w], (1.0f - wwr*erw), wwr*wvw);
    #pragma unroll
    for(int r=0;r<NR;r++) acc[r] = fmaf(s_nrw[r][jl], nmv, acc[r]);
  }
  #pragma unroll
  for(int r=0;r<NR;r++) s_acc[wv][r][w] = acc[r];
  __syncthreads();
  {
    int r = tid>>6, k = tid&63;
    float s = s_acc[0][r][k]+s_acc[1][r][k]+s_acc[2][r][k]+s_acc[3][r][k];
    atomicAdd(&out[b*NR*NW + r*NW + k], s);
  }
}

extern "C" void kernel_launch(void* const* d_in, const int* in_sizes, int n_in,
                              void* d_out, int out_size, void* d_ws, size_t ws_size,
                              hipStream_t stream) {
  (void)in_sizes; (void)n_in; (void)out_size; (void)ws_size;
  const float* xi   = (const float*)d_in[0];
  const float* Wm   = (const float*)d_in[1];
  const float* bW   = (const float*)d_in[2];
  const float* mem  = (const float*)d_in[3];
  const float* link = (const float*)d_in[4];
  const float* prec = (const float*)d_in[5];
  const float* rw   = (const float*)d_in[6];
  const float* wwo  = (const float*)d_in[7];
  const float* uv   = (const float*)d_in[8];
  float* out = (float*)d_out;
  float* ws  = (float*)d_ws;
  float* iface = ws;                  // 30208
  float* wwp   = ws + 30208;          // 65536
  float* uu    = ws + 95744;          // 65536
  float* wcd   = ws + 161280;         // 65536
  float* wcn   = ws + 226816;         // 65536
  float* ce    = ws + 292352;         // 262144 = [b][4][1024]
  float* ldiag = ws + 554496;         // 65536
  float* sPK   = ws + 620032;         // 1024 = [b][16]
  float* RFp   = ws + 621056;         // 4*262144 (float4-aligned)
  float* C2p   = ws + 1669632;        // 4*262144
  float* C3p   = ws + 2718208;        // 4*262144
  k_iface<<<dim3(NB,2), 256, 0, stream>>>(xi, Wm, bW, iface, (float4*)out);
  k_wcos <<<dim3(4,NB), 256, 0, stream>>>(iface, mem, rw, wwo, uv, uu, wcd, wcn);
  k_write2<<<NB, 1024, 0, stream>>>(iface, uu, wcd, wcn, wwp, sPK);
  k_link8<<<dim3(4,4,NB), 256, 0, stream>>>(link, rw, wwp, (float4*)RFp, C2p, C3p, ldiag);
  k_rdots2<<<dim3(4,NB), 256, 0, stream>>>(iface, mem, wwp, prec, rw, ce, sPK);
  k_readf<<<dim3(4,NB), 256, 0, stream>>>(iface, mem, wwp, prec, rw, ldiag,
                                          (const float4*)RFp, C2p, C3p, ce, sPK, out);
}